// Round 2
// baseline (53.587 us; speedup 1.0000x reference)
//
#include <hip/hip_runtime.h>
#include <stdint.h>

// SActv: packed stochastic-computing bitstream, 9 right-rolled copies -> MAJ3 tree.
// For MSB-first packing, a right-roll by s (0<=s<32) of the whole bit sequence is,
// per 32-bit word i:  O_s[i] = ((uint64(W[i-1 mod NW]) << 32) | W[i]) >> s
// i.e. a funnel shift (v_alignbit_b32). Each output word needs only (prev, cur).

#define NUM_INTS 256  // words per row (fixed by reference: stream is (batch, 256))

__device__ __forceinline__ uint32_t maj3(uint32_t a, uint32_t b, uint32_t c) {
    return (a & b) | (a & c) | (b & c);
}

__device__ __forceinline__ uint32_t fsh(uint32_t hi, uint32_t lo, uint32_t s) {
    // funnel shift right: low 32 bits of ((hi:lo) >> s); s in [0, 8] here, no UB.
    return (uint32_t)(((((uint64_t)hi) << 32) | (uint64_t)lo) >> s);
}

__device__ __forceinline__ uint32_t compute_word(uint32_t prev, uint32_t cur) {
    // 9 shifted streams s=0..8, grouped (0,1,2)(3,4,5)(6,7,8) -> maj3 -> maj3.
    uint32_t m[3];
#pragma unroll
    for (int g = 0; g < 3; ++g) {
        uint32_t a = fsh(prev, cur, 3 * g + 0);
        uint32_t b = fsh(prev, cur, 3 * g + 1);
        uint32_t c = fsh(prev, cur, 3 * g + 2);
        m[g] = maj3(a, b, c);
    }
    return maj3(m[0], m[1], m[2]);
}

__global__ __launch_bounds__(256) void sactv_kernel(const uint32_t* __restrict__ in,
                                                    uint32_t* __restrict__ out,
                                                    int total_groups) {
    int stride = gridDim.x * blockDim.x;
    for (int gid = blockIdx.x * blockDim.x + threadIdx.x; gid < total_groups; gid += stride) {
        int row = gid >> 6;            // NUM_INTS/4 = 64 uint4-groups per row
        int grp = gid & 63;
        int base = (row << 8) + (grp << 2);
        uint4 v = *reinterpret_cast<const uint4*>(in + base);
        // predecessor word of the group, wrapping within the row
        uint32_t prev0 = (grp == 0) ? in[(row << 8) + NUM_INTS - 1] : in[base - 1];
        uint4 o;
        o.x = compute_word(prev0, v.x);
        o.y = compute_word(v.x, v.y);
        o.z = compute_word(v.y, v.z);
        o.w = compute_word(v.z, v.w);
        *reinterpret_cast<uint4*>(out + base) = o;
    }
}

extern "C" void kernel_launch(void* const* d_in, const int* in_sizes, int n_in,
                              void* d_out, int out_size, void* d_ws, size_t ws_size,
                              hipStream_t stream) {
    const uint32_t* in = (const uint32_t*)d_in[0];
    uint32_t* out = (uint32_t*)d_out;
    int total_words = in_sizes[0];            // batch * NUM_INTS
    int total_groups = total_words >> 2;      // 4 words per thread
    int block = 256;
    int grid = (total_groups + block - 1) / block;
    sactv_kernel<<<grid, block, 0, stream>>>(in, out, total_groups);
}